// Round 5
// baseline (1819.484 us; speedup 1.0000x reference)
//
#include <hip/hip_runtime.h>
#include <hip/hip_bf16.h>

#define DIM 256
#define HEADS 8
#define DH 32
#define AGENT 6
#define WIN 7
#define NTOK 294              // AGENT*WIN*WIN
#define BWIN 128              // B*X*Y = 2*8*8
#define NTILE 7
#define NN (NTOK*NTOK)        // 86436
#define KSTR 33               // padded LDS row stride for K/V (conflict-free)
#define SCALE 0.17677669529663687f  // 32^-0.5

typedef __hip_bfloat16 bf16;

__device__ __forceinline__ float bf_lo(unsigned int p){ return __uint_as_float(p << 16); }
__device__ __forceinline__ float bf_hi(unsigned int p){ return __uint_as_float(p & 0xffff0000u); }
__device__ __forceinline__ float bfv(unsigned short u){ return __uint_as_float(((unsigned int)u) << 16); }

// ---------- dtype detector: read x as bf16; f32 data shows huge/NaN even elements ----------
// flag = 1  -> inputs are float32 ; flag = 0 -> inputs are bf16
__global__ void detect_kernel(const unsigned short* __restrict__ xraw, int* __restrict__ flag) {
    __shared__ int s;
    if (threadIdx.x == 0) s = 0;
    __syncthreads();
    int bad = 0;
    for (int i = threadIdx.x; i < 8192; i += 256) {
        float v = bfv(xraw[i]);
        if (!(fabsf(v) <= 1e10f)) bad = 1;   // catches huge, inf, NaN
    }
    if (bad) atomicOr(&s, 1);
    __syncthreads();
    if (threadIdx.x == 0) *flag = s;
}

// ---------- bias expansion: biasM[h][i][j] = bias_table[rel_idx(i,j)][h] (stored bf16) ----------
__global__ void bias_kernel(const void* __restrict__ bt, bf16* __restrict__ biasM,
                            const int* __restrict__ flag) {
    int idx = blockIdx.x * 256 + threadIdx.x;
    if (idx >= NN) return;
    const int isf32 = *flag;
    int i = idx / NTOK, j = idx - i * NTOK;
    int li = i / 49, ri = i - li * 49, w1i = ri / 7, w2i = ri - w1i * 7;
    int lj = j / 49, rj = j - lj * 49, w1j = rj / 7, w2j = rj - w1j * 7;
    int rel = (li - lj + AGENT - 1) * 169 + (w1i - w1j + WIN - 1) * 13 + (w2i - w2j + WIN - 1);
    #pragma unroll
    for (int h = 0; h < HEADS; h++) {
        float v;
        if (isf32) v = ((const float*)bt)[rel * HEADS + h];
        else       v = bfv(((const unsigned short*)bt)[rel * HEADS + h]);
        biasM[(size_t)h * NN + idx] = __float2bfloat16(v);
    }
}

#define QKV_FMA(CC)                                                             \
    {   const int c_ = (CC);                                                    \
        _Pragma("unroll")                                                       \
        for (int r = 0; r < NTILE; r++) {                                       \
            const float* xr = &xs[r * DIM + c_];                                \
            acc[r] += xr[0]*wv0 + xr[1]*wv1 + xr[2]*wv2 + xr[3]*wv3             \
                    + xr[4]*wv4 + xr[5]*wv5 + xr[6]*wv6 + xr[7]*wv7;            \
        } }

// ---------- QKV projection: x @ w_qkv^T -> Q(scaled)/K/V bf16 in (bw,h,n,d) ----------
__global__ __launch_bounds__(256) void qkv_kernel(
    const void* __restrict__ xin, const void* __restrict__ wqkv,
    bf16* __restrict__ Q, bf16* __restrict__ K, bf16* __restrict__ V,
    const int* __restrict__ flag) {
    __shared__ float xs[NTILE * DIM];
    const int tid = threadIdx.x;
    const int blk = blockIdx.x;
    const int isf32 = *flag;
    const int bw = blk / 42;
    const int tile = blk - bw * 42;            // tile = l*7 + w1 ; rows are w2 = 0..6
    const int b = bw >> 6, xx = (bw >> 3) & 7, yy = bw & 7;
    const int l = tile / 7, w1 = tile - l * 7;
    const size_t tokbase = ((((size_t)b * AGENT + l) * 8 + xx) * 8 + yy) * 49 + (size_t)(w1 * 7);
    if (isf32) {
        const float* xg = (const float*)xin + tokbase * DIM;
        for (int g = tid; g < NTILE * DIM / 4; g += 256)
            ((float4*)xs)[g] = ((const float4*)xg)[g];
    } else {
        if (tid < NTILE * DIM / 8) {           // 224 threads unpack 8 bf16 each
            const unsigned short* xg = (const unsigned short*)xin + tokbase * DIM;
            uint4 u = ((const uint4*)xg)[tid];
            int o = tid * 8;
            xs[o + 0] = bf_lo(u.x); xs[o + 1] = bf_hi(u.x);
            xs[o + 2] = bf_lo(u.y); xs[o + 3] = bf_hi(u.y);
            xs[o + 4] = bf_lo(u.z); xs[o + 5] = bf_hi(u.z);
            xs[o + 6] = bf_lo(u.w); xs[o + 7] = bf_hi(u.w);
        }
    }
    __syncthreads();
    const int h = tid >> 5, d = tid & 31;
    const int n0 = tile * 7;
    bf16* const dsts[3] = {Q, K, V};
    #pragma unroll
    for (int p = 0; p < 3; p++) {
        const int row = p * DIM + tid;
        float acc[NTILE];
        #pragma unroll
        for (int r = 0; r < NTILE; r++) acc[r] = 0.f;
        if (isf32) {
            const float4* wrow = (const float4*)((const float*)wqkv + (size_t)row * DIM);
            #pragma unroll 2
            for (int c8 = 0; c8 < DIM / 8; c8++) {
                float4 u0 = wrow[2 * c8], u1 = wrow[2 * c8 + 1];
                float wv0 = u0.x, wv1 = u0.y, wv2 = u0.z, wv3 = u0.w,
                      wv4 = u1.x, wv5 = u1.y, wv6 = u1.z, wv7 = u1.w;
                QKV_FMA(c8 * 8)
            }
        } else {
            const uint4* wrow = (const uint4*)((const unsigned short*)wqkv + (size_t)row * DIM);
            #pragma unroll 2
            for (int c8 = 0; c8 < DIM / 8; c8++) {
                uint4 u = wrow[c8];
                float wv0 = bf_lo(u.x), wv1 = bf_hi(u.x), wv2 = bf_lo(u.y), wv3 = bf_hi(u.y),
                      wv4 = bf_lo(u.z), wv5 = bf_hi(u.z), wv6 = bf_lo(u.w), wv7 = bf_hi(u.w);
                QKV_FMA(c8 * 8)
            }
        }
        const float sc = (p == 0) ? SCALE : 1.0f;
        bf16* dst = dsts[p] + (((size_t)bw * HEADS + h) * NTOK + n0) * DH + d;
        #pragma unroll
        for (int r = 0; r < NTILE; r++) dst[(size_t)r * DH] = __float2bfloat16(acc[r] * sc);
    }
}

// ---------- attention: per (bw,h) block, QK^T + bias + mask -> softmax -> @V ----------
__global__ __launch_bounds__(512) void attn_kernel(
    const bf16* __restrict__ Q, const bf16* __restrict__ K, const bf16* __restrict__ V,
    const bf16* __restrict__ biasM, const int* __restrict__ mask, bf16* __restrict__ AT) {
    __shared__ float Qs[NTOK * DH];           // stride 32: broadcast-only, b128-aligned
    __shared__ float Ks[NTOK * KSTR];         // stride 33: conflict-free lane-strided reads
    __shared__ float Vs[NTOK * KSTR];
    __shared__ float pbuf[8 * NTOK * 4];      // per-wave P rows, float4-packed [j][r]
    __shared__ int   ms[NTOK];
    const int tid = threadIdx.x;
    const int blk = blockIdx.x;
    const int bw = blk >> 3, h = blk & 7;
    const size_t base = ((size_t)bw * HEADS + h) * NTOK * DH;
    const unsigned int* Qg = (const unsigned int*)(Q + base);   // 2 bf16 per uint
    const unsigned int* Kg = (const unsigned int*)(K + base);
    const unsigned int* Vg = (const unsigned int*)(V + base);
    for (int gg = tid; gg < NTOK * DH / 2; gg += 512) {
        int r = gg >> 4, d2 = (gg & 15) * 2;
        unsigned int uq = Qg[gg], uk = Kg[gg], uv = Vg[gg];
        Qs[r * DH + d2] = bf_lo(uq);   Qs[r * DH + d2 + 1] = bf_hi(uq);
        Ks[r * KSTR + d2] = bf_lo(uk); Ks[r * KSTR + d2 + 1] = bf_hi(uk);
        Vs[r * KSTR + d2] = bf_lo(uv); Vs[r * KSTR + d2 + 1] = bf_hi(uv);
    }
    for (int j = tid; j < NTOK; j += 512) {
        int lj = j / 49, rr = j - lj * 49;
        ms[j] = mask[((size_t)bw * 49 + rr) * AGENT + lj];
    }
    __syncthreads();
    const int wave = tid >> 6, lane = tid & 63;
    const int dcol = lane & 31, half = lane >> 5;
    const unsigned short* bias_h = (const unsigned short*)biasM + (size_t)h * NN;
    const int j4 = lane + 256;                 // 5th key column (294 = 4*64 + 38)
    float* pw = pbuf + wave * (NTOK * 4);
    for (int it = 0; it < 10; it++) {          // fixed trip count: all waves hit barriers
        const int i0 = wave * 4 + it * 32;
        const bool act = (i0 < NTOK);          // wave-uniform
        float inv[4];
        int ric[4]; bool rv[4];
        if (act) {
            float s[4][5];
            #pragma unroll
            for (int r = 0; r < 4; r++)
                #pragma unroll
                for (int t = 0; t < 5; t++) s[r][t] = 0.f;
            #pragma unroll
            for (int r = 0; r < 4; r++) { int ii = i0 + r; rv[r] = ii < NTOK; ric[r] = rv[r] ? ii : NTOK - 1; }
            // ---- QK^T, key cols lane+64t (t<4 always in range) ----
            #pragma unroll
            for (int dc = 0; dc < DH; dc += 4) {
                float4 q0 = *(const float4*)&Qs[ric[0] * DH + dc];
                float4 q1 = *(const float4*)&Qs[ric[1] * DH + dc];
                float4 q2 = *(const float4*)&Qs[ric[2] * DH + dc];
                float4 q3 = *(const float4*)&Qs[ric[3] * DH + dc];
                #pragma unroll
                for (int t = 0; t < 4; t++) {
                    const float* kr = &Ks[(lane + 64 * t) * KSTR + dc];
                    float k0 = kr[0], k1 = kr[1], k2 = kr[2], k3 = kr[3];
                    s[0][t] += q0.x*k0 + q0.y*k1 + q0.z*k2 + q0.w*k3;
                    s[1][t] += q1.x*k0 + q1.y*k1 + q1.z*k2 + q1.w*k3;
                    s[2][t] += q2.x*k0 + q2.y*k1 + q2.z*k2 + q2.w*k3;
                    s[3][t] += q3.x*k0 + q3.y*k1 + q3.z*k2 + q3.w*k3;
                }
            }
            if (j4 < NTOK) {
                const float* kr = &Ks[j4 * KSTR];
                #pragma unroll
                for (int dc = 0; dc < DH; dc += 4) {
                    float4 q0 = *(const float4*)&Qs[ric[0] * DH + dc];
                    float4 q1 = *(const float4*)&Qs[ric[1] * DH + dc];
                    float4 q2 = *(const float4*)&Qs[ric[2] * DH + dc];
                    float4 q3 = *(const float4*)&Qs[ric[3] * DH + dc];
                    float k0 = kr[dc], k1 = kr[dc + 1], k2 = kr[dc + 2], k3 = kr[dc + 3];
                    s[0][4] += q0.x*k0 + q0.y*k1 + q0.z*k2 + q0.w*k3;
                    s[1][4] += q1.x*k0 + q1.y*k1 + q1.z*k2 + q1.w*k3;
                    s[2][4] += q2.x*k0 + q2.y*k1 + q2.z*k2 + q2.w*k3;
                    s[3][4] += q3.x*k0 + q3.y*k1 + q3.z*k2 + q3.w*k3;
                }
            }
            // ---- bias then hard mask (-1e9 replaces, matching reference order) ----
            #pragma unroll
            for (int r = 0; r < 4; r++) {
                const unsigned short* bi = bias_h + (size_t)ric[r] * NTOK;
                #pragma unroll
                for (int t = 0; t < 4; t++) {
                    int j = lane + 64 * t;
                    float sv = s[r][t] + bfv(bi[j]);
                    s[r][t] = (ms[j] == 0) ? -1e9f : sv;
                }
                if (j4 < NTOK) {
                    float sv = s[r][4] + bfv(bi[j4]);
                    s[r][4] = (ms[j4] == 0) ? -1e9f : sv;
                } else {
                    s[r][4] = -1e30f;   // out-of-range key: exp -> 0
                }
            }
            // ---- softmax (per row, 64-lane shuffle reductions) ----
            #pragma unroll
            for (int r = 0; r < 4; r++) {
                float m = fmaxf(fmaxf(fmaxf(s[r][0], s[r][1]), fmaxf(s[r][2], s[r][3])), s[r][4]);
                #pragma unroll
                for (int o = 32; o > 0; o >>= 1) m = fmaxf(m, __shfl_xor(m, o));
                float p0 = __expf(s[r][0] - m), p1 = __expf(s[r][1] - m), p2 = __expf(s[r][2] - m),
                      p3 = __expf(s[r][3] - m), p4 = __expf(s[r][4] - m);
                s[r][0] = p0; s[r][1] = p1; s[r][2] = p2; s[r][3] = p3; s[r][4] = p4;
                float sum = ((p0 + p1) + (p2 + p3)) + p4;
                #pragma unroll
                for (int o = 32; o > 0; o >>= 1) sum += __shfl_xor(sum, o);
                inv[r] = 1.0f / sum;
            }
            // ---- stash P (j -> d transpose via LDS), float4 packed over the 4 rows ----
            #pragma unroll
            for (int t = 0; t < 4; t++)
                *(float4*)&pw[(lane + 64 * t) * 4] = make_float4(s[0][t], s[1][t], s[2][t], s[3][t]);
            if (j4 < NTOK)
                *(float4*)&pw[j4 * 4] = make_float4(s[0][4], s[1][4], s[2][4], s[3][4]);
        }
        __syncthreads();                       // stash visible to all lanes of the wave
        if (act) {
            // ---- P @ V : lanes split d (32) x j-halves (147 each) ----
            float a0 = 0.f, a1 = 0.f, a2 = 0.f, a3 = 0.f;
            const int jb = half * 147;
            #pragma unroll 3
            for (int jj = 0; jj < 147; jj++) {
                int j = jb + jj;
                float vv = Vs[j * KSTR + dcol];
                float4 pj = *(const float4*)&pw[j * 4];
                a0 += pj.x * vv; a1 += pj.y * vv; a2 += pj.z * vv; a3 += pj.w * vv;
            }
            float accs[4] = {a0, a1, a2, a3};
            #pragma unroll
            for (int r = 0; r < 4; r++) {
                float a = accs[r] + __shfl_xor(accs[r], 32);
                a *= inv[r];
                if (lane < 32 && rv[r])
                    AT[((size_t)bw * NTOK + (i0 + r)) * DIM + h * DH + dcol] = __float2bfloat16(a);
            }
        }
        __syncthreads();                       // PV reads done before next iteration's stash
    }
}

#define PROJ_FMA(CC)                                                            \
    {   const int c_ = (CC);                                                    \
        _Pragma("unroll")                                                       \
        for (int r = 0; r < NTILE; r++) {                                       \
            const float* ar = &as_[r * DIM + c_];                               \
            acc[r] += ar[0]*wv0 + ar[1]*wv1 + ar[2]*wv2 + ar[3]*wv3             \
                    + ar[4]*wv4 + ar[5]*wv5 + ar[6]*wv6 + ar[7]*wv7;            \
        } }

// ---------- output projection + layout restore (OUTPUT IS FLOAT32) ----------
__global__ __launch_bounds__(256) void proj_kernel(
    const bf16* __restrict__ AT, const void* __restrict__ wout,
    float* __restrict__ out, const int* __restrict__ flag) {
    __shared__ float as_[NTILE * DIM];
    const int tid = threadIdx.x;
    const int blk = blockIdx.x;
    const int isf32 = *flag;
    const int bw = blk / 42;
    const int tile = blk - bw * 42;
    const int b = bw >> 6, xx = (bw >> 3) & 7, yy = bw & 7;
    const int l = tile / 7, w1 = tile - l * 7;
    const int n0 = tile * 7;
    const unsigned short* ag = (const unsigned short*)(AT + ((size_t)bw * NTOK + n0) * DIM);
    if (tid < NTILE * DIM / 8) {               // 224 threads unpack 8 bf16 each
        uint4 u = ((const uint4*)ag)[tid];
        int o = tid * 8;
        as_[o + 0] = bf_lo(u.x); as_[o + 1] = bf_hi(u.x);
        as_[o + 2] = bf_lo(u.y); as_[o + 3] = bf_hi(u.y);
        as_[o + 4] = bf_lo(u.z); as_[o + 5] = bf_hi(u.z);
        as_[o + 6] = bf_lo(u.w); as_[o + 7] = bf_hi(u.w);
    }
    __syncthreads();
    float acc[NTILE];
    #pragma unroll
    for (int r = 0; r < NTILE; r++) acc[r] = 0.f;
    if (isf32) {
        const float4* wrow = (const float4*)((const float*)wout + (size_t)tid * DIM);
        #pragma unroll 2
        for (int c8 = 0; c8 < DIM / 8; c8++) {
            float4 u0 = wrow[2 * c8], u1 = wrow[2 * c8 + 1];
            float wv0 = u0.x, wv1 = u0.y, wv2 = u0.z, wv3 = u0.w,
                  wv4 = u1.x, wv5 = u1.y, wv6 = u1.z, wv7 = u1.w;
            PROJ_FMA(c8 * 8)
        }
    } else {
        const uint4* wrow = (const uint4*)((const unsigned short*)wout + (size_t)tid * DIM);
        #pragma unroll 2
        for (int c8 = 0; c8 < DIM / 8; c8++) {
            uint4 u = wrow[c8];
            float wv0 = bf_lo(u.x), wv1 = bf_hi(u.x), wv2 = bf_lo(u.y), wv3 = bf_hi(u.y),
                  wv4 = bf_lo(u.z), wv5 = bf_hi(u.z), wv6 = bf_lo(u.w), wv7 = bf_hi(u.w);
            PROJ_FMA(c8 * 8)
        }
    }
    const size_t obase = (((((size_t)b * AGENT + l) * 8 + xx) * 8 + yy) * 49 + (size_t)(w1 * 7)) * DIM;
    #pragma unroll
    for (int r = 0; r < NTILE; r++)
        out[obase + (size_t)r * DIM + tid] = acc[r];     // f32 store — output dtype fix
}

extern "C" void kernel_launch(void* const* d_in, const int* in_sizes, int n_in,
                              void* d_out, int out_size, void* d_ws, size_t ws_size,
                              hipStream_t stream) {
    // Resolve inputs by element count (all five are distinct); fall back to position.
    const long long SZ_X = 9633792, SZ_M = 37632, SZ_WQ = 196608, SZ_WO = 65536, SZ_BT = 14872;
    const void* x = d_in[0]; const void* maskp = d_in[1]; const void* wqkv = d_in[2];
    const void* wout = d_in[3]; const void* btab = d_in[4];
    for (int i = 0; i < n_in; i++) {
        long long s = in_sizes[i];
        if (s == SZ_X) x = d_in[i];
        else if (s == SZ_M) maskp = d_in[i];
        else if (s == SZ_WQ) wqkv = d_in[i];
        else if (s == SZ_WO) wout = d_in[i];
        else if (s == SZ_BT) btab = d_in[i];
    }
    const int* mask = (const int*)maskp;
    float* out = (float*)d_out;                 // reference output dtype: float32
    // workspace (all bf16): Q,K,V,AT each BWIN*NTOK*DIM + biasM 8*NN + flag  ~= 78.5 MB
    const size_t SZ = (size_t)BWIN * NTOK * DIM;   // 9,633,792
    bf16* Q     = (bf16*)d_ws;
    bf16* K     = Q + SZ;
    bf16* V     = K + SZ;
    bf16* AT    = V + SZ;
    bf16* biasM = AT + SZ;
    int*  flag  = (int*)(biasM + (size_t)HEADS * NN);
    detect_kernel<<<dim3(1), dim3(256), 0, stream>>>((const unsigned short*)x, flag);
    bias_kernel<<<dim3((NN + 255) / 256), dim3(256), 0, stream>>>(btab, biasM, flag);
    qkv_kernel<<<dim3(BWIN * 42), dim3(256), 0, stream>>>(x, wqkv, Q, K, V, flag);
    attn_kernel<<<dim3(BWIN * HEADS), dim3(512), 0, stream>>>(Q, K, V, biasM, mask, AT);
    proj_kernel<<<dim3(BWIN * 42), dim3(256), 0, stream>>>(AT, wout, out, flag);
}

// Round 6
// 823.642 us; speedup vs baseline: 2.2091x; 2.2091x over previous
//
#include <hip/hip_runtime.h>
#include <hip/hip_bf16.h>

#define DIM 256
#define HEADS 8
#define DH 32
#define AGENT 6
#define WIN 7
#define NTOK 294              // AGENT*WIN*WIN
#define BWIN 128              // B*X*Y = 2*8*8
#define NTILE 7
#define NN (NTOK*NTOK)
#define SCALE 0.17677669529663687f  // 32^-0.5
#define TP 19                 // 16-row tiles covering 294 (padded to 304)
#define QSTR 40               // Qs/Ks LDS row stride (elems): 80B, 16B-aligned, 2-way banks
#define PSTR 328              // P/Vt LDS row stride (elems): 656B, 16B-aligned, 2-way banks

typedef __hip_bfloat16 bf16;
typedef __attribute__((ext_vector_type(8))) short s16x8;
typedef __attribute__((ext_vector_type(4))) float f32x4;

__device__ __forceinline__ float bf_lo(unsigned int p){ return __uint_as_float(p << 16); }
__device__ __forceinline__ float bf_hi(unsigned int p){ return __uint_as_float(p & 0xffff0000u); }
__device__ __forceinline__ float bfv(unsigned short u){ return __uint_as_float(((unsigned int)u) << 16); }
__device__ __forceinline__ unsigned short f2bu(float f){
    bf16 b = __float2bfloat16(f); return *reinterpret_cast<unsigned short*>(&b);
}
__device__ __forceinline__ float rdf(const void* p, size_t idx, int isf32) {
    return isf32 ? ((const float*)p)[idx] : bfv(((const unsigned short*)p)[idx]);
}

// ---------- dtype detector: flag=1 -> f32 inputs, flag=0 -> bf16 ----------
__global__ void detect_kernel(const unsigned short* __restrict__ xraw, int* __restrict__ flag) {
    __shared__ int s;
    if (threadIdx.x == 0) s = 0;
    __syncthreads();
    int bad = 0;
    for (int i = threadIdx.x; i < 8192; i += 256) {
        float v = bfv(xraw[i]);
        if (!(fabsf(v) <= 1e10f)) bad = 1;
    }
    if (bad) atomicOr(&s, 1);
    __syncthreads();
    if (threadIdx.x == 0) *flag = s;
}

// ---------- bias in MFMA C-fragment order: biasB[h][it][jt][lane][reg] (bf16) ----------
// C/D layout (m89): col=lane&15 -> i (query), row=(lane>>4)*4+reg -> j (key)
__global__ void biasb_kernel(const void* __restrict__ bt, unsigned short* __restrict__ biasB,
                             const int* __restrict__ flag) {
    int idx = blockIdx.x * 256 + threadIdx.x;          // one ushort4 per idx
    const int total = HEADS * TP * TP * 64;
    if (idx >= total) return;
    const int isf32 = *flag;
    int lane = idx & 63; int t = idx >> 6;
    int jt = t % TP; t /= TP; int it = t % TP; int h = t / TP;
    int i = it * 16 + (lane & 15);
    int g = lane >> 4;
    ushort4 v;
    unsigned short* vp = (unsigned short*)&v;
    #pragma unroll
    for (int r = 0; r < 4; r++) {
        int j = jt * 16 + g * 4 + r;
        float val = 0.f;
        if (i < NTOK && j < NTOK) {
            int li = i / 49, ri = i - li * 49, w1i = ri / 7, w2i = ri - w1i * 7;
            int lj = j / 49, rj = j - lj * 49, w1j = rj / 7, w2j = rj - w1j * 7;
            int rel = (li - lj + AGENT - 1) * 169 + (w1i - w1j + WIN - 1) * 13 + (w2i - w2j + WIN - 1);
            val = rdf(bt, (size_t)rel * HEADS + h, isf32);
        }
        vp[r] = f2bu(val);
    }
    ((ushort4*)biasB)[idx] = v;
}

#define QKV_FMA(CC)                                                             \
    {   const int c_ = (CC);                                                    \
        _Pragma("unroll")                                                       \
        for (int r = 0; r < NTILE; r++) {                                       \
            const float* xr = &xs[r * DIM + c_];                                \
            acc[r] += xr[0]*wv0 + xr[1]*wv1 + xr[2]*wv2 + xr[3]*wv3             \
                    + xr[4]*wv4 + xr[5]*wv5 + xr[6]*wv6 + xr[7]*wv7;            \
        } }

// ---------- QKV projection (unchanged from R5) ----------
__global__ __launch_bounds__(256) void qkv_kernel(
    const void* __restrict__ xin, const void* __restrict__ wqkv,
    bf16* __restrict__ Q, bf16* __restrict__ K, bf16* __restrict__ V,
    const int* __restrict__ flag) {
    __shared__ float xs[NTILE * DIM];
    const int tid = threadIdx.x;
    const int blk = blockIdx.x;
    const int isf32 = *flag;
    const int bw = blk / 42;
    const int tile = blk - bw * 42;
    const int b = bw >> 6, xx = (bw >> 3) & 7, yy = bw & 7;
    const int l = tile / 7, w1 = tile - l * 7;
    const size_t tokbase = ((((size_t)b * AGENT + l) * 8 + xx) * 8 + yy) * 49 + (size_t)(w1 * 7);
    if (isf32) {
        const float* xg = (const float*)xin + tokbase * DIM;
        for (int g = tid; g < NTILE * DIM / 4; g += 256)
            ((float4*)xs)[g] = ((const float4*)xg)[g];
    } else {
        if (tid < NTILE * DIM / 8) {
            const unsigned short* xg = (const unsigned short*)xin + tokbase * DIM;
            uint4 u = ((const uint4*)xg)[tid];
            int o = tid * 8;
            xs[o + 0] = bf_lo(u.x); xs[o + 1] = bf_hi(u.x);
            xs[o + 2] = bf_lo(u.y); xs[o + 3] = bf_hi(u.y);
            xs[o + 4] = bf_lo(u.z); xs[o + 5] = bf_hi(u.z);
            xs[o + 6] = bf_lo(u.w); xs[o + 7] = bf_hi(u.w);
        }
    }
    __syncthreads();
    const int h = tid >> 5, d = tid & 31;
    const int n0 = tile * 7;
    bf16* const dsts[3] = {Q, K, V};
    #pragma unroll
    for (int p = 0; p < 3; p++) {
        const int row = p * DIM + tid;
        float acc[NTILE];
        #pragma unroll
        for (int r = 0; r < NTILE; r++) acc[r] = 0.f;
        if (isf32) {
            const float4* wrow = (const float4*)((const float*)wqkv + (size_t)row * DIM);
            #pragma unroll 2
            for (int c8 = 0; c8 < DIM / 8; c8++) {
                float4 u0 = wrow[2 * c8], u1 = wrow[2 * c8 + 1];
                float wv0 = u0.x, wv1 = u0.y, wv2 = u0.z, wv3 = u0.w,
                      wv4 = u1.x, wv5 = u1.y, wv6 = u1.z, wv7 = u1.w;
                QKV_FMA(c8 * 8)
            }
        } else {
            const uint4* wrow = (const uint4*)((const unsigned short*)wqkv + (size_t)row * DIM);
            #pragma unroll 2
            for (int c8 = 0; c8 < DIM / 8; c8++) {
                uint4 u = wrow[c8];
                float wv0 = bf_lo(u.x), wv1 = bf_hi(u.x), wv2 = bf_lo(u.y), wv3 = bf_hi(u.y),
                      wv4 = bf_lo(u.z), wv5 = bf_hi(u.z), wv6 = bf_lo(u.w), wv7 = bf_hi(u.w);
                QKV_FMA(c8 * 8)
            }
        }
        const float sc = (p == 0) ? SCALE : 1.0f;
        bf16* dst = dsts[p] + (((size_t)bw * HEADS + h) * NTOK + n0) * DH + d;
        #pragma unroll
        for (int r = 0; r < NTILE; r++) dst[(size_t)r * DH] = __float2bfloat16(acc[r] * sc);
    }
}

// ---------- MFMA attention: per (bw,h) block; S^T = K·Q^T (+bias C-init), softmax, O = P·V ----------
__global__ __launch_bounds__(512) void attn_mfma(
    const bf16* __restrict__ Q, const bf16* __restrict__ K, const bf16* __restrict__ V,
    const unsigned short* __restrict__ biasB, const int* __restrict__ mask,
    bf16* __restrict__ AT) {
    __shared__ unsigned short Qs[304 * QSTR];       // [i][d]
    __shared__ unsigned short Ks[304 * QSTR];       // [j][d]
    __shared__ unsigned short Vt[32 * PSTR];        // [d][j] transposed
    __shared__ unsigned short Pl[8 * 16 * PSTR];    // per-wave P[i][j]
    __shared__ int ms[320];
    const int tid = threadIdx.x;
    const int bw = blockIdx.x >> 3, h = blockIdx.x & 7;
    const size_t base = ((size_t)bw * HEADS + h) * NTOK * DH;
    const unsigned int* Qg = (const unsigned int*)(Q + base);
    const unsigned int* Kg = (const unsigned int*)(K + base);
    const unsigned int* Vg = (const unsigned int*)(V + base);
    for (int gg = tid; gg < NTOK * DH / 2; gg += 512) {
        int r = gg >> 4, d2 = (gg & 15) * 2;
        *(unsigned int*)&Qs[r * QSTR + d2] = Qg[gg];
        *(unsigned int*)&Ks[r * QSTR + d2] = Kg[gg];
        unsigned int uv = Vg[gg];
        Vt[d2 * PSTR + r]       = (unsigned short)(uv & 0xffffu);
        Vt[(d2 + 1) * PSTR + r] = (unsigned short)(uv >> 16);
    }
    for (int e = NTOK * QSTR + tid; e < 304 * QSTR; e += 512) { Qs[e] = 0; Ks[e] = 0; }
    for (int idx = tid; idx < 32 * (PSTR - NTOK); idx += 512) {
        int d = idx / (PSTR - NTOK), c = NTOK + idx % (PSTR - NTOK);
        Vt[d * PSTR + c] = 0;
    }
    for (int idx = tid; idx < 128 * (PSTR - 304); idx += 512) {
        int rr = idx / (PSTR - 304), c = 304 + idx % (PSTR - 304);
        Pl[rr * PSTR + c] = 0;
    }
    for (int j = tid; j < 320; j += 512) {
        int mv = 0;
        if (j < NTOK) { int a = j / 49, jr = j - a * 49; mv = mask[((size_t)bw * 49 + jr) * AGENT + a]; }
        ms[j] = mv;
    }
    __syncthreads();
    const int wave = tid >> 6, lane = tid & 63;
    const int li = lane & 15, g = lane >> 4;
    unsigned short* Pw = &Pl[wave * 16 * PSTR];
    // static per-lane mask bits: bit jt*4+r  (j = jt*16 + g*4 + r)
    unsigned int mb0 = 0, mb1 = 0, mb2 = 0;
    for (int jt = 0; jt < TP; jt++)
        for (int r = 0; r < 4; r++) {
            int j = jt * 16 + g * 4 + r;
            if (j < NTOK && ms[j]) {
                int bit = jt * 4 + r;
                if (bit < 32) mb0 |= (1u << bit);
                else if (bit < 64) mb1 |= (1u << (bit - 32));
                else mb2 |= (1u << (bit - 64));
            }
        }
    const ushort4* bb = (const ushort4*)biasB + (size_t)h * TP * TP * 64;
    for (int it = wave; it < TP; it += 8) {
        // B-frag: Q^T, n=i=it*16+li, k=d=g*8..+7  (one load, reused for all jt)
        const s16x8 bq = *(const s16x8*)&Qs[(it * 16 + li) * QSTR + g * 8];
        f32x4 s[TP];
        #pragma unroll
        for (int jt = 0; jt < TP; jt++) {
            ushort4 bv = bb[(it * TP + jt) * 64 + lane];
            f32x4 c = {bfv(bv.x), bfv(bv.y), bfv(bv.z), bfv(bv.w)};
            s16x8 ak = *(const s16x8*)&Ks[(jt * 16 + li) * QSTR + g * 8];
            s[jt] = __builtin_amdgcn_mfma_f32_16x16x32_bf16(ak, bq, c, 0, 0, 0);
        }
        // mask (-1e9 replaces, ref order) and j-padding (-inf -> exp 0)
        float mx = -INFINITY;
        #pragma unroll
        for (int jt = 0; jt < TP; jt++)
            #pragma unroll
            for (int r = 0; r < 4; r++) {
                int bit = jt * 4 + r;
                unsigned int w = (bit < 32) ? mb0 : (bit < 64) ? mb1 : mb2;
                float sv = ((w >> (bit & 31)) & 1u) ? s[jt][r] : -1e9f;
                if (jt == TP - 1 && g * 4 + r >= 6) sv = -INFINITY;   // j >= 294
                s[jt][r] = sv;
                mx = fmaxf(mx, sv);
            }
        mx = fmaxf(mx, __shfl_xor(mx, 16));
        mx = fmaxf(mx, __shfl_xor(mx, 32));
        float sum = 0.f;
        #pragma unroll
        for (int jt = 0; jt < TP; jt++)
            #pragma unroll
            for (int r = 0; r < 4; r++) {
                float e = __expf(s[jt][r] - mx);
                s[jt][r] = e;
                sum += e;
            }
        sum += __shfl_xor(sum, 16);
        sum += __shfl_xor(sum, 32);
        const float inv = 1.0f / sum;
        // P (normalized, bf16) -> per-wave LDS in A-operand row-major [i][j]
        #pragma unroll
        for (int jt = 0; jt < TP; jt++) {
            ushort4 pv;
            pv.x = f2bu(s[jt][0] * inv); pv.y = f2bu(s[jt][1] * inv);
            pv.z = f2bu(s[jt][2] * inv); pv.w = f2bu(s[jt][3] * inv);
            *(ushort4*)&Pw[li * PSTR + jt * 16 + g * 4] = pv;
        }
        // O = P·V : A from Pw rows (m=i=li), B from Vt rows (n=d=li / li+16)
        f32x4 o0 = {0.f, 0.f, 0.f, 0.f}, o1 = {0.f, 0.f, 0.f, 0.f};
        #pragma unroll
        for (int kc = 0; kc < 10; kc++) {
            s16x8 ap = *(const s16x8*)&Pw[li * PSTR + kc * 32 + g * 8];
            s16x8 b0 = *(const s16x8*)&Vt[li * PSTR + kc * 32 + g * 8];
            s16x8 b1 = *(const s16x8*)&Vt[(li + 16) * PSTR + kc * 32 + g * 8];
            o0 = __builtin_amdgcn_mfma_f32_16x16x32_bf16(ap, b0, o0, 0, 0, 0);
            o1 = __builtin_amdgcn_mfma_f32_16x16x32_bf16(ap, b1, o1, 0, 0, 0);
        }
        #pragma unroll
        for (int r = 0; r < 4; r++) {
            int i = it * 16 + g * 4 + r;
            if (i < NTOK) {
                size_t ob = ((size_t)bw * NTOK + i) * DIM + h * DH;
                AT[ob + li]      = __float2bfloat16(o0[r]);
                AT[ob + 16 + li] = __float2bfloat16(o1[r]);
            }
        }
    }
}

#define PROJ_FMA(CC)                                                            \
    {   const int c_ = (CC);                                                    \
        _Pragma("unroll")                                                       \
        for (int r = 0; r < NTILE; r++) {                                       \
            const float* ar = &as_[r * DIM + c_];                               \
            acc[r] += ar[0]*wv0 + ar[1]*wv1 + ar[2]*wv2 + ar[3]*wv3             \
                    + ar[4]*wv4 + ar[5]*wv5 + ar[6]*wv6 + ar[7]*wv7;            \
        } }

// ---------- output projection + layout restore (f32 output), unchanged ----------
__global__ __launch_bounds__(256) void proj_kernel(
    const bf16* __restrict__ AT, const void* __restrict__ wout,
    float* __restrict__ out, const int* __restrict__ flag) {
    __shared__ float as_[NTILE * DIM];
    const int tid = threadIdx.x;
    const int blk = blockIdx.x;
    const int isf32 = *flag;
    const int bw = blk / 42;
    const int tile = blk - bw * 42;
    const int b = bw >> 6, xx = (bw >> 3) & 7, yy = bw & 7;
    const int l = tile / 7, w1 = tile - l * 7;
    const int n0 = tile * 7;
    const unsigned short* ag = (const unsigned short*)(AT + ((size_t)bw * NTOK + n0) * DIM);
    if (tid < NTILE * DIM / 8) {
        uint4 u = ((const uint4*)ag)[tid];
        int o = tid * 8;
        as_[o + 0] = bf_lo(u.x); as_[o + 1] = bf_hi(u.x);
        as_[o + 2] = bf_lo(u.y); as_[o + 3] = bf_hi(u.y);
        as_[o + 4] = bf_lo(u.z); as_[o + 5] = bf_hi(u.z);
        as_[o + 6] = bf_lo(u.w); as_[o + 7] = bf_hi(u.w);
    }
    __syncthreads();
    float acc[NTILE];
    #pragma unroll
    for (int r = 0; r < NTILE; r++) acc[r] = 0.f;
    if (isf32) {
        const float4* wrow = (const float4*)((const float*)wout + (size_t)tid * DIM);
        #pragma unroll 2
        for (int c8 = 0; c8 < DIM / 8; c8++) {
            float4 u0 = wrow[2 * c8], u1 = wrow[2 * c8 + 1];
            float wv0 = u0.x, wv1 = u0.y, wv2 = u0.z, wv3 = u0.w,
                  wv4 = u1.x, wv5 = u1.y, wv6 = u1.z, wv7 = u1.w;
            PROJ_FMA(c8 * 8)
        }
    } else {
        const uint4* wrow = (const uint4*)((const unsigned short*)wout + (size_t)tid * DIM);
        #pragma unroll 2
        for (int c8 = 0; c8 < DIM / 8; c8++) {
            uint4 u = wrow[c8];
            float wv0 = bf_lo(u.x), wv1 = bf_hi(u.x), wv2 = bf_lo(u.y), wv3 = bf_hi(u.y),
                  wv4 = bf_lo(u.z), wv5 = bf_hi(u.z), wv6 = bf_lo(u.w), wv7 = bf_hi(u.w);
            PROJ_FMA(c8 * 8)
        }
    }
    const size_t obase = (((((size_t)b * AGENT + l) * 8 + xx) * 8 + yy) * 49 + (size_t)(w1 * 7)) * DIM;
    #pragma unroll
    for (int r = 0; r < NTILE; r++)
        out[obase + (size_t)r * DIM + tid] = acc[r];
}

extern "C" void kernel_launch(void* const* d_in, const int* in_sizes, int n_in,
                              void* d_out, int out_size, void* d_ws, size_t ws_size,
                              hipStream_t stream) {
    const long long SZ_X = 9633792, SZ_M = 37632, SZ_WQ = 196608, SZ_WO = 65536, SZ_BT = 14872;
    const void* x = d_in[0]; const void* maskp = d_in[1]; const void* wqkv = d_in[2];
    const void* wout = d_in[3]; const void* btab = d_in[4];
    for (int i = 0; i < n_in; i++) {
        long long s = in_sizes[i];
        if (s == SZ_X) x = d_in[i];
        else if (s == SZ_M) maskp = d_in[i];
        else if (s == SZ_WQ) wqkv = d_in[i];
        else if (s == SZ_WO) wout = d_in[i];
        else if (s == SZ_BT) btab = d_in[i];
    }
    const int* mask = (const int*)maskp;
    float* out = (float*)d_out;
    // ws: Q,K,V,AT bf16 (4 x 9,633,792) + biasB bf16 (8*19*19*64*4) + flag  ~= 78.5 MB
    const size_t SZ = (size_t)BWIN * NTOK * DIM;
    bf16* Q  = (bf16*)d_ws;
    bf16* K  = Q + SZ;
    bf16* V  = K + SZ;
    bf16* AT = V + SZ;
    unsigned short* biasB = (unsigned short*)(AT + SZ);
    const size_t NBB = (size_t)HEADS * TP * TP * 64 * 4;   // 739,328 bf16
    int* flag = (int*)(biasB + NBB);
    detect_kernel<<<dim3(1), dim3(256), 0, stream>>>((const unsigned short*)x, flag);
    biasb_kernel<<<dim3((HEADS * TP * TP * 64 + 255) / 256), dim3(256), 0, stream>>>(btab, biasB, flag);
    qkv_kernel<<<dim3(BWIN * 42), dim3(256), 0, stream>>>(x, wqkv, Q, K, V, flag);
    attn_mfma<<<dim3(BWIN * HEADS), dim3(512), 0, stream>>>(Q, K, V, biasB, mask, AT);
    proj_kernel<<<dim3(BWIN * 42), dim3(256), 0, stream>>>(AT, wout, out, flag);
}

// Round 7
// 349.589 us; speedup vs baseline: 5.2046x; 2.3560x over previous
//
#include <hip/hip_runtime.h>
#include <hip/hip_bf16.h>

#define DIM 256
#define HEADS 8
#define DH 32
#define AGENT 6
#define WIN 7
#define NTOK 294              // AGENT*WIN*WIN
#define BWIN 128              // B*X*Y = 2*8*8
#define NN (NTOK*NTOK)
#define SCALE 0.17677669529663687f  // 32^-0.5
#define TP 19                 // 16-row tiles covering 294 (padded to 304)
#define QSTR 40               // attn Qs/Ks LDS row stride
#define PSTR 328              // attn P/Vt LDS row stride
#define GST 264               // GEMM LDS row stride (elems): 528B, 16B-aligned, 2-way banks
#define NTOKENS 37632         // BWIN * NTOK = 588 * 64

typedef __hip_bfloat16 bf16;
typedef __attribute__((ext_vector_type(8))) short s16x8;
typedef __attribute__((ext_vector_type(4))) float f32x4;

__device__ __forceinline__ float bf_lo(unsigned int p){ return __uint_as_float(p << 16); }
__device__ __forceinline__ float bf_hi(unsigned int p){ return __uint_as_float(p & 0xffff0000u); }
__device__ __forceinline__ float bfv(unsigned short u){ return __uint_as_float(((unsigned int)u) << 16); }
__device__ __forceinline__ unsigned short f2bu(float f){
    bf16 b = __float2bfloat16(f); return *reinterpret_cast<unsigned short*>(&b);
}
__device__ __forceinline__ float rdf(const void* p, size_t idx, int isf32) {
    return isf32 ? ((const float*)p)[idx] : bfv(((const unsigned short*)p)[idx]);
}

// ---------- dtype detector: flag=1 -> f32 inputs, flag=0 -> bf16 ----------
__global__ void detect_kernel(const unsigned short* __restrict__ xraw, int* __restrict__ flag) {
    __shared__ int s;
    if (threadIdx.x == 0) s = 0;
    __syncthreads();
    int bad = 0;
    for (int i = threadIdx.x; i < 8192; i += 256) {
        float v = bfv(xraw[i]);
        if (!(fabsf(v) <= 1e10f)) bad = 1;
    }
    if (bad) atomicOr(&s, 1);
    __syncthreads();
    if (threadIdx.x == 0) *flag = s;
}

// ---------- bias in MFMA C-fragment order: biasB[h][it][jt][lane][reg] (bf16) ----------
__global__ void biasb_kernel(const void* __restrict__ bt, unsigned short* __restrict__ biasB,
                             const int* __restrict__ flag) {
    int idx = blockIdx.x * 256 + threadIdx.x;
    const int total = HEADS * TP * TP * 64;
    if (idx >= total) return;
    const int isf32 = *flag;
    int lane = idx & 63; int t = idx >> 6;
    int jt = t % TP; t /= TP; int it = t % TP; int h = t / TP;
    int i = it * 16 + (lane & 15);
    int g = lane >> 4;
    ushort4 v;
    unsigned short* vp = (unsigned short*)&v;
    #pragma unroll
    for (int r = 0; r < 4; r++) {
        int j = jt * 16 + g * 4 + r;
        float val = 0.f;
        if (i < NTOK && j < NTOK) {
            int li = i / 49, ri = i - li * 49, w1i = ri / 7, w2i = ri - w1i * 7;
            int lj = j / 49, rj = j - lj * 49, w1j = rj / 7, w2j = rj - w1j * 7;
            int rel = (li - lj + AGENT - 1) * 169 + (w1i - w1j + WIN - 1) * 13 + (w2i - w2j + WIN - 1);
            val = rdf(bt, (size_t)rel * HEADS + h, isf32);
        }
        vp[r] = f2bu(val);
    }
    ((ushort4*)biasB)[idx] = v;
}

// ---------- QKV MFMA GEMM: C[m,e] = sum_c x[m,c]*wqkv[e,c]; 64x64 tile, K=256 ----------
// grid: mTile (588) x eTile (12);  scatter epilogue into Q/K/V (bw,h,n,d) bf16
__global__ __launch_bounds__(256) void qkv_mfma(
    const void* __restrict__ xin, const void* __restrict__ wqkv,
    bf16* __restrict__ Q, bf16* __restrict__ K, bf16* __restrict__ V,
    const int* __restrict__ flag) {
    __shared__ unsigned short As[64 * GST];
    __shared__ unsigned short Bs[64 * GST];
    __shared__ int bwA[64], nA[64];
    const int tid = threadIdx.x;
    const int isf32 = *flag;
    const int eTile = blockIdx.x % 12, mTile = blockIdx.x / 12;
    const int mBase = mTile * 64, eBase = eTile * 64;
    // token LUT for the 64 rows (x-order m -> bw, n)
    if (tid < 64) {
        int m = mBase + tid;
        int w2 = m % 7; int t1 = m / 7; int w1 = t1 % 7; int t2 = t1 / 7;
        int yy = t2 & 7; int t3 = t2 >> 3; int xx = t3 & 7; int t4 = t3 >> 3;
        int l = t4 % 6; int b = t4 / 6;
        bwA[tid] = (b << 6) | (xx << 3) | yy;
        nA[tid] = l * 49 + w1 * 7 + w2;
    }
    // stage A (x rows, cvt to bf16) and B (w rows)
    {
        const int row = tid >> 2, cq = (tid & 3) * 64;
        if (isf32) {
            const float4* a4 = (const float4*)((const float*)xin + (size_t)(mBase + row) * DIM + cq);
            const float4* b4 = (const float4*)((const float*)wqkv + (size_t)(eBase + row) * DIM + cq);
            unsigned short* ad = &As[row * GST + cq];
            unsigned short* bd = &Bs[row * GST + cq];
            #pragma unroll
            for (int i = 0; i < 16; i++) {
                float4 va = a4[i], vb = b4[i];
                ushort4 ua = {f2bu(va.x), f2bu(va.y), f2bu(va.z), f2bu(va.w)};
                ushort4 ub = {f2bu(vb.x), f2bu(vb.y), f2bu(vb.z), f2bu(vb.w)};
                *(ushort4*)&ad[i * 4] = ua;
                *(ushort4*)&bd[i * 4] = ub;
            }
        } else {
            const uint4* a4 = (const uint4*)((const unsigned short*)xin + (size_t)(mBase + row) * DIM + cq);
            const uint4* b4 = (const uint4*)((const unsigned short*)wqkv + (size_t)(eBase + row) * DIM + cq);
            unsigned short* ad = &As[row * GST + cq];
            unsigned short* bd = &Bs[row * GST + cq];
            #pragma unroll
            for (int i = 0; i < 8; i++) {
                *(uint4*)&ad[i * 8] = a4[i];
                *(uint4*)&bd[i * 8] = b4[i];
            }
        }
    }
    __syncthreads();
    const int wave = tid >> 6, lane = tid & 63;
    const int li = lane & 15, g = lane >> 4;
    const int wm = wave & 1, wn = wave >> 1;
    f32x4 acc[2][2];
    #pragma unroll
    for (int mi = 0; mi < 2; mi++)
        #pragma unroll
        for (int ni = 0; ni < 2; ni++) acc[mi][ni] = (f32x4){0.f, 0.f, 0.f, 0.f};
    #pragma unroll
    for (int kc = 0; kc < 8; kc++) {
        const int ko = kc * 32 + g * 8;
        s16x8 a0 = *(const s16x8*)&As[(wm * 32 + li) * GST + ko];
        s16x8 a1 = *(const s16x8*)&As[(wm * 32 + 16 + li) * GST + ko];
        s16x8 b0 = *(const s16x8*)&Bs[(wn * 32 + li) * GST + ko];
        s16x8 b1 = *(const s16x8*)&Bs[(wn * 32 + 16 + li) * GST + ko];
        acc[0][0] = __builtin_amdgcn_mfma_f32_16x16x32_bf16(a0, b0, acc[0][0], 0, 0, 0);
        acc[0][1] = __builtin_amdgcn_mfma_f32_16x16x32_bf16(a0, b1, acc[0][1], 0, 0, 0);
        acc[1][0] = __builtin_amdgcn_mfma_f32_16x16x32_bf16(a1, b0, acc[1][0], 0, 0, 0);
        acc[1][1] = __builtin_amdgcn_mfma_f32_16x16x32_bf16(a1, b1, acc[1][1], 0, 0, 0);
    }
    // epilogue: e = eBase + wn*32 + ni*16 + li ; m = mBase + wm*32 + mi*16 + g*4 + r
    const int p = eBase >> 8;                       // 0:Q 1:K 2:V (64 | 256)
    bf16* dst = (p == 0) ? Q : (p == 1) ? K : V;
    const float sc = (p == 0) ? SCALE : 1.0f;
    const int h = ((eBase & 255) + wn * 32) >> 5;   // ni*16+li < 32: same h
    #pragma unroll
    for (int ni = 0; ni < 2; ni++) {
        const int d = ni * 16 + li;
        #pragma unroll
        for (int mi = 0; mi < 2; mi++)
            #pragma unroll
            for (int r = 0; r < 4; r++) {
                int ml = wm * 32 + mi * 16 + g * 4 + r;
                dst[(((size_t)bwA[ml] * HEADS + h) * NTOK + nA[ml]) * DH + d] =
                    __float2bfloat16(acc[mi][ni][r] * sc);
            }
    }
}

// ---------- MFMA attention (unchanged from R6) ----------
__global__ __launch_bounds__(512) void attn_mfma(
    const bf16* __restrict__ Q, const bf16* __restrict__ K, const bf16* __restrict__ V,
    const unsigned short* __restrict__ biasB, const int* __restrict__ mask,
    bf16* __restrict__ AT) {
    __shared__ unsigned short Qs[304 * QSTR];
    __shared__ unsigned short Ks[304 * QSTR];
    __shared__ unsigned short Vt[32 * PSTR];
    __shared__ unsigned short Pl[8 * 16 * PSTR];
    __shared__ int ms[320];
    const int tid = threadIdx.x;
    const int bw = blockIdx.x >> 3, h = blockIdx.x & 7;
    const size_t base = ((size_t)bw * HEADS + h) * NTOK * DH;
    const unsigned int* Qg = (const unsigned int*)(Q + base);
    const unsigned int* Kg = (const unsigned int*)(K + base);
    const unsigned int* Vg = (const unsigned int*)(V + base);
    for (int gg = tid; gg < NTOK * DH / 2; gg += 512) {
        int r = gg >> 4, d2 = (gg & 15) * 2;
        *(unsigned int*)&Qs[r * QSTR + d2] = Qg[gg];
        *(unsigned int*)&Ks[r * QSTR + d2] = Kg[gg];
        unsigned int uv = Vg[gg];
        Vt[d2 * PSTR + r]       = (unsigned short)(uv & 0xffffu);
        Vt[(d2 + 1) * PSTR + r] = (unsigned short)(uv >> 16);
    }
    for (int e = NTOK * QSTR + tid; e < 304 * QSTR; e += 512) { Qs[e] = 0; Ks[e] = 0; }
    for (int idx = tid; idx < 32 * (PSTR - NTOK); idx += 512) {
        int d = idx / (PSTR - NTOK), c = NTOK + idx % (PSTR - NTOK);
        Vt[d * PSTR + c] = 0;
    }
    for (int idx = tid; idx < 128 * (PSTR - 304); idx += 512) {
        int rr = idx / (PSTR - 304), c = 304 + idx % (PSTR - 304);
        Pl[rr * PSTR + c] = 0;
    }
    for (int j = tid; j < 320; j += 512) {
        int mv = 0;
        if (j < NTOK) { int a = j / 49, jr = j - a * 49; mv = mask[((size_t)bw * 49 + jr) * AGENT + a]; }
        ms[j] = mv;
    }
    __syncthreads();
    const int wave = tid >> 6, lane = tid & 63;
    const int li = lane & 15, g = lane >> 4;
    unsigned short* Pw = &Pl[wave * 16 * PSTR];
    unsigned int mb0 = 0, mb1 = 0, mb2 = 0;
    for (int jt = 0; jt < TP; jt++)
        for (int r = 0; r < 4; r++) {
            int j = jt * 16 + g * 4 + r;
            if (j < NTOK && ms[j]) {
                int bit = jt * 4 + r;
                if (bit < 32) mb0 |= (1u << bit);
                else if (bit < 64) mb1 |= (1u << (bit - 32));
                else mb2 |= (1u << (bit - 64));
            }
        }
    const ushort4* bb = (const ushort4*)biasB + (size_t)h * TP * TP * 64;
    for (int it = wave; it < TP; it += 8) {
        const s16x8 bq = *(const s16x8*)&Qs[(it * 16 + li) * QSTR + g * 8];
        f32x4 s[TP];
        #pragma unroll
        for (int jt = 0; jt < TP; jt++) {
            ushort4 bv = bb[(it * TP + jt) * 64 + lane];
            f32x4 c = {bfv(bv.x), bfv(bv.y), bfv(bv.z), bfv(bv.w)};
            s16x8 ak = *(const s16x8*)&Ks[(jt * 16 + li) * QSTR + g * 8];
            s[jt] = __builtin_amdgcn_mfma_f32_16x16x32_bf16(ak, bq, c, 0, 0, 0);
        }
        float mx = -INFINITY;
        #pragma unroll
        for (int jt = 0; jt < TP; jt++)
            #pragma unroll
            for (int r = 0; r < 4; r++) {
                int bit = jt * 4 + r;
                unsigned int w = (bit < 32) ? mb0 : (bit < 64) ? mb1 : mb2;
                float sv = ((w >> (bit & 31)) & 1u) ? s[jt][r] : -1e9f;
                if (jt == TP - 1 && g * 4 + r >= 6) sv = -INFINITY;
                s[jt][r] = sv;
                mx = fmaxf(mx, sv);
            }
        mx = fmaxf(mx, __shfl_xor(mx, 16));
        mx = fmaxf(mx, __shfl_xor(mx, 32));
        float sum = 0.f;
        #pragma unroll
        for (int jt = 0; jt < TP; jt++)
            #pragma unroll
            for (int r = 0; r < 4; r++) {
                float e = __expf(s[jt][r] - mx);
                s[jt][r] = e;
                sum += e;
            }
        sum += __shfl_xor(sum, 16);
        sum += __shfl_xor(sum, 32);
        const float inv = 1.0f / sum;
        #pragma unroll
        for (int jt = 0; jt < TP; jt++) {
            ushort4 pv;
            pv.x = f2bu(s[jt][0] * inv); pv.y = f2bu(s[jt][1] * inv);
            pv.z = f2bu(s[jt][2] * inv); pv.w = f2bu(s[jt][3] * inv);
            *(ushort4*)&Pw[li * PSTR + jt * 16 + g * 4] = pv;
        }
        f32x4 o0 = {0.f, 0.f, 0.f, 0.f}, o1 = {0.f, 0.f, 0.f, 0.f};
        #pragma unroll
        for (int kc = 0; kc < 10; kc++) {
            s16x8 ap = *(const s16x8*)&Pw[li * PSTR + kc * 32 + g * 8];
            s16x8 b0 = *(const s16x8*)&Vt[li * PSTR + kc * 32 + g * 8];
            s16x8 b1 = *(const s16x8*)&Vt[(li + 16) * PSTR + kc * 32 + g * 8];
            o0 = __builtin_amdgcn_mfma_f32_16x16x32_bf16(ap, b0, o0, 0, 0, 0);
            o1 = __builtin_amdgcn_mfma_f32_16x16x32_bf16(ap, b1, o1, 0, 0, 0);
        }
        #pragma unroll
        for (int r = 0; r < 4; r++) {
            int i = it * 16 + g * 4 + r;
            if (i < NTOK) {
                size_t ob = ((size_t)bw * NTOK + i) * DIM + h * DH;
                AT[ob + li]      = __float2bfloat16(o0[r]);
                AT[ob + 16 + li] = __float2bfloat16(o1[r]);
            }
        }
    }
}

// ---------- proj MFMA GEMM: out[tok,e] = sum_c AT[row,c]*wout[e,c]; 64x64 tile ----------
// grid: mTile (588) x eTile (4); A rows are (bw,n)-order bf16; f32 scatter to x-order
__global__ __launch_bounds__(256) void proj_mfma(
    const bf16* __restrict__ AT, const void* __restrict__ wout,
    float* __restrict__ out, const int* __restrict__ flag) {
    __shared__ unsigned short As[64 * GST];
    __shared__ unsigned short Bs[64 * GST];
    __shared__ int offA[64];
    const int tid = threadIdx.x;
    const int isf32 = *flag;
    const int eTile = blockIdx.x & 3, mTile = blockIdx.x >> 2;
    const int mBase = mTile * 64, eBase = eTile * 64;
    if (tid < 64) {
        int row = mBase + tid;                  // (bw, n) order
        int bw = row / NTOK, n = row - bw * NTOK;
        int b = bw >> 6, xx = (bw >> 3) & 7, yy = bw & 7;
        int l = n / 49, rr = n - l * 49, w1 = rr / 7, w2 = rr - w1 * 7;
        offA[tid] = ((((b * AGENT + l) * 8 + xx) * 8 + yy) * 7 + w1) * 7 + w2;
    }
    {
        const int row = tid >> 2, cq = (tid & 3) * 64;
        const uint4* a4 = (const uint4*)((const unsigned short*)AT + (size_t)(mBase + row) * DIM + cq);
        unsigned short* ad = &As[row * GST + cq];
        #pragma unroll
        for (int i = 0; i < 8; i++) *(uint4*)&ad[i * 8] = a4[i];
        unsigned short* bd = &Bs[row * GST + cq];
        if (isf32) {
            const float4* b4 = (const float4*)((const float*)wout + (size_t)(eBase + row) * DIM + cq);
            #pragma unroll
            for (int i = 0; i < 16; i++) {
                float4 vb = b4[i];
                ushort4 ub = {f2bu(vb.x), f2bu(vb.y), f2bu(vb.z), f2bu(vb.w)};
                *(ushort4*)&bd[i * 4] = ub;
            }
        } else {
            const uint4* b4 = (const uint4*)((const unsigned short*)wout + (size_t)(eBase + row) * DIM + cq);
            #pragma unroll
            for (int i = 0; i < 8; i++) *(uint4*)&bd[i * 8] = b4[i];
        }
    }
    __syncthreads();
    const int wave = tid >> 6, lane = tid & 63;
    const int li = lane & 15, g = lane >> 4;
    const int wm = wave & 1, wn = wave >> 1;
    f32x4 acc[2][2];
    #pragma unroll
    for (int mi = 0; mi < 2; mi++)
        #pragma unroll
        for (int ni = 0; ni < 2; ni++) acc[mi][ni] = (f32x4){0.f, 0.f, 0.f, 0.f};
    #pragma unroll
    for (int kc = 0; kc < 8; kc++) {
        const int ko = kc * 32 + g * 8;
        s16x8 a0 = *(const s16x8*)&As[(wm * 32 + li) * GST + ko];
        s16x8 a1 = *(const s16x8*)&As[(wm * 32 + 16 + li) * GST + ko];
        s16x8 b0 = *(const s16x8*)&Bs[(wn * 32 + li) * GST + ko];
        s16x8 b1 = *(const s16x8*)&Bs[(wn * 32 + 16 + li) * GST + ko];
        acc[0][0] = __builtin_amdgcn_mfma_f32_16x16x32_bf16(a0, b0, acc[0][0], 0, 0, 0);
        acc[0][1] = __builtin_amdgcn_mfma_f32_16x16x32_bf16(a0, b1, acc[0][1], 0, 0, 0);
        acc[1][0] = __builtin_amdgcn_mfma_f32_16x16x32_bf16(a1, b0, acc[1][0], 0, 0, 0);
        acc[1][1] = __builtin_amdgcn_mfma_f32_16x16x32_bf16(a1, b1, acc[1][1], 0, 0, 0);
    }
    #pragma unroll
    for (int ni = 0; ni < 2; ni++) {
        const int e = eBase + wn * 32 + ni * 16 + li;
        #pragma unroll
        for (int mi = 0; mi < 2; mi++)
            #pragma unroll
            for (int r = 0; r < 4; r++) {
                int ml = wm * 32 + mi * 16 + g * 4 + r;
                out[(size_t)offA[ml] * DIM + e] = acc[mi][ni][r];
            }
    }
}

extern "C" void kernel_launch(void* const* d_in, const int* in_sizes, int n_in,
                              void* d_out, int out_size, void* d_ws, size_t ws_size,
                              hipStream_t stream) {
    const long long SZ_X = 9633792, SZ_M = 37632, SZ_WQ = 196608, SZ_WO = 65536, SZ_BT = 14872;
    const void* x = d_in[0]; const void* maskp = d_in[1]; const void* wqkv = d_in[2];
    const void* wout = d_in[3]; const void* btab = d_in[4];
    for (int i = 0; i < n_in; i++) {
        long long s = in_sizes[i];
        if (s == SZ_X) x = d_in[i];
        else if (s == SZ_M) maskp = d_in[i];
        else if (s == SZ_WQ) wqkv = d_in[i];
        else if (s == SZ_WO) wout = d_in[i];
        else if (s == SZ_BT) btab = d_in[i];
    }
    const int* mask = (const int*)maskp;
    float* out = (float*)d_out;
    const size_t SZ = (size_t)BWIN * NTOK * DIM;
    bf16* Q  = (bf16*)d_ws;
    bf16* K  = Q + SZ;
    bf16* V  = K + SZ;
    bf16* AT = V + SZ;
    unsigned short* biasB = (unsigned short*)(AT + SZ);
    const size_t NBB = (size_t)HEADS * TP * TP * 64 * 4;
    int* flag = (int*)(biasB + NBB);
    detect_kernel<<<dim3(1), dim3(256), 0, stream>>>((const unsigned short*)x, flag);
    biasb_kernel<<<dim3((HEADS * TP * TP * 64 + 255) / 256), dim3(256), 0, stream>>>(btab, biasB, flag);
    qkv_mfma<<<dim3(588 * 12), dim3(256), 0, stream>>>(x, wqkv, Q, K, V, flag);
    attn_mfma<<<dim3(BWIN * HEADS), dim3(512), 0, stream>>>(Q, K, V, biasB, mask, AT);
    proj_mfma<<<dim3(588 * 4), dim3(256), 0, stream>>>(AT, wout, out, flag);
}

// Round 8
// 314.471 us; speedup vs baseline: 5.7859x; 1.1117x over previous
//
#include <hip/hip_runtime.h>
#include <hip/hip_bf16.h>

#define DIM 256
#define HEADS 8
#define DH 32
#define AGENT 6
#define WIN 7
#define NTOK 294              // AGENT*WIN*WIN
#define BWIN 128              // B*X*Y = 2*8*8
#define NN (NTOK*NTOK)
#define SCALE 0.17677669529663687f  // 32^-0.5
#define TP 19                 // 16-row tiles covering 294 (padded to 304)
#define QSTR 40               // attn Qs/Ks LDS row stride
#define PSTR 328              // attn P/Vt LDS row stride
#define GST 264               // GEMM LDS row stride (elems): 528B, 16B-aligned

typedef __hip_bfloat16 bf16;
typedef __attribute__((ext_vector_type(8))) short s16x8;
typedef __attribute__((ext_vector_type(4))) float f32x4;

__device__ __forceinline__ float bf_lo(unsigned int p){ return __uint_as_float(p << 16); }
__device__ __forceinline__ float bf_hi(unsigned int p){ return __uint_as_float(p & 0xffff0000u); }
__device__ __forceinline__ float bfv(unsigned short u){ return __uint_as_float(((unsigned int)u) << 16); }
__device__ __forceinline__ unsigned short f2bu(float f){
    bf16 b = __float2bfloat16(f); return *reinterpret_cast<unsigned short*>(&b);
}
__device__ __forceinline__ float rdf(const void* p, size_t idx, int isf32) {
    return isf32 ? ((const float*)p)[idx] : bfv(((const unsigned short*)p)[idx]);
}

// ---------- dtype detector: flag=1 -> f32 inputs, flag=0 -> bf16 ----------
__global__ void detect_kernel(const unsigned short* __restrict__ xraw, int* __restrict__ flag) {
    __shared__ int s;
    if (threadIdx.x == 0) s = 0;
    __syncthreads();
    int bad = 0;
    for (int i = threadIdx.x; i < 8192; i += 256) {
        float v = bfv(xraw[i]);
        if (!(fabsf(v) <= 1e10f)) bad = 1;
    }
    if (bad) atomicOr(&s, 1);
    __syncthreads();
    if (threadIdx.x == 0) *flag = s;
}

// ---------- bias in MFMA C-fragment order: biasB[h][it][jt][lane][reg] (bf16) ----------
__global__ void biasb_kernel(const void* __restrict__ bt, unsigned short* __restrict__ biasB,
                             const int* __restrict__ flag) {
    int idx = blockIdx.x * 256 + threadIdx.x;
    const int total = HEADS * TP * TP * 64;
    if (idx >= total) return;
    const int isf32 = *flag;
    int lane = idx & 63; int t = idx >> 6;
    int jt = t % TP; t /= TP; int it = t % TP; int h = t / TP;
    int i = it * 16 + (lane & 15);
    int g = lane >> 4;
    ushort4 v;
    unsigned short* vp = (unsigned short*)&v;
    #pragma unroll
    for (int r = 0; r < 4; r++) {
        int j = jt * 16 + g * 4 + r;
        float val = 0.f;
        if (i < NTOK && j < NTOK) {
            int li = i / 49, ri = i - li * 49, w1i = ri / 7, w2i = ri - w1i * 7;
            int lj = j / 49, rj = j - lj * 49, w1j = rj / 7, w2j = rj - w1j * 7;
            int rel = (li - lj + AGENT - 1) * 169 + (w1i - w1j + WIN - 1) * 13 + (w2i - w2j + WIN - 1);
            val = rdf(bt, (size_t)rel * HEADS + h, isf32);
        }
        vp[r] = f2bu(val);
    }
    ((ushort4*)biasB)[idx] = v;
}

// stage one 64x256 tile (f32->bf16 or bf16 copy) into LDS, conflict-free:
// thread handles 8 consecutive elems; consecutive tids -> consecutive 16B
__device__ __forceinline__ void stage_tile(unsigned short* dst, const void* src,
                                           size_t rowBase, int isf32) {
    const int tid = threadIdx.x;
    #pragma unroll
    for (int itr = 0; itr < 8; itr++) {
        int ch = itr * 256 + tid;
        int row = ch >> 5, cc = (ch & 31) * 8;
        unsigned short* d = &dst[row * GST + cc];
        if (isf32) {
            const float4* s4 = (const float4*)((const float*)src + (rowBase + row) * DIM + cc);
            float4 v0 = s4[0], v1 = s4[1];
            ushort4 u0 = {f2bu(v0.x), f2bu(v0.y), f2bu(v0.z), f2bu(v0.w)};
            ushort4 u1 = {f2bu(v1.x), f2bu(v1.y), f2bu(v1.z), f2bu(v1.w)};
            *(ushort4*)d = u0; *(ushort4*)(d + 4) = u1;
        } else {
            *(uint4*)d = *(const uint4*)((const unsigned short*)src + (rowBase + row) * DIM + cc);
        }
    }
}

// ---------- QKV MFMA GEMM: stage x-tile once, loop 12 e-chunks in-block ----------
__global__ __launch_bounds__(256) void qkv_mfma(
    const void* __restrict__ xin, const void* __restrict__ wqkv,
    bf16* __restrict__ Q, bf16* __restrict__ K, bf16* __restrict__ V,
    const int* __restrict__ flag) {
    __shared__ unsigned short As[64 * GST];
    __shared__ unsigned short Bs[64 * GST];
    __shared__ int bwA[64], nA[64];
    const int tid = threadIdx.x;
    const int isf32 = *flag;
    const int mBase = blockIdx.x * 64;
    if (tid < 64) {
        int m = mBase + tid;
        int w2 = m % 7; int t1 = m / 7; int w1 = t1 % 7; int t2 = t1 / 7;
        int yy = t2 & 7; int t3 = t2 >> 3; int xx = t3 & 7; int t4 = t3 >> 3;
        int l = t4 % 6; int b = t4 / 6;
        bwA[tid] = (b << 6) | (xx << 3) | yy;
        nA[tid] = l * 49 + w1 * 7 + w2;
    }
    stage_tile(As, xin, (size_t)mBase, isf32);
    const int wave = tid >> 6, lane = tid & 63;
    const int li = lane & 15, g = lane >> 4;
    const int wm = wave & 1, wn = wave >> 1;
    for (int pc = 0; pc < 12; pc++) {
        __syncthreads();                       // prev chunk's reads done (also covers As staging)
        stage_tile(Bs, wqkv, (size_t)pc * 64, isf32);
        __syncthreads();
        f32x4 acc[2][2];
        #pragma unroll
        for (int mi = 0; mi < 2; mi++)
            #pragma unroll
            for (int ni = 0; ni < 2; ni++) acc[mi][ni] = (f32x4){0.f, 0.f, 0.f, 0.f};
        #pragma unroll
        for (int kc = 0; kc < 8; kc++) {
            const int ko = kc * 32 + g * 8;
            s16x8 a0 = *(const s16x8*)&As[(wm * 32 + li) * GST + ko];
            s16x8 a1 = *(const s16x8*)&As[(wm * 32 + 16 + li) * GST + ko];
            s16x8 b0 = *(const s16x8*)&Bs[(wn * 32 + li) * GST + ko];
            s16x8 b1 = *(const s16x8*)&Bs[(wn * 32 + 16 + li) * GST + ko];
            acc[0][0] = __builtin_amdgcn_mfma_f32_16x16x32_bf16(a0, b0, acc[0][0], 0, 0, 0);
            acc[0][1] = __builtin_amdgcn_mfma_f32_16x16x32_bf16(a0, b1, acc[0][1], 0, 0, 0);
            acc[1][0] = __builtin_amdgcn_mfma_f32_16x16x32_bf16(a1, b0, acc[1][0], 0, 0, 0);
            acc[1][1] = __builtin_amdgcn_mfma_f32_16x16x32_bf16(a1, b1, acc[1][1], 0, 0, 0);
        }
        const int p = pc >> 2;                  // 0:Q 1:K 2:V
        bf16* dst = (p == 0) ? Q : (p == 1) ? K : V;
        const float sc = (p == 0) ? SCALE : 1.0f;
        const int h = (pc & 3) * 2 + wn;        // e_local = (pc&3)*64 + wn*32 + ni*16+li
        #pragma unroll
        for (int ni = 0; ni < 2; ni++) {
            const int d = ni * 16 + li;
            #pragma unroll
            for (int mi = 0; mi < 2; mi++)
                #pragma unroll
                for (int r = 0; r < 4; r++) {
                    int ml = wm * 32 + mi * 16 + g * 4 + r;
                    dst[(((size_t)bwA[ml] * HEADS + h) * NTOK + nA[ml]) * DH + d] =
                        __float2bfloat16(acc[mi][ni][r] * sc);
                }
        }
    }
}

// ---------- MFMA attention (unchanged from R7) ----------
__global__ __launch_bounds__(512) void attn_mfma(
    const bf16* __restrict__ Q, const bf16* __restrict__ K, const bf16* __restrict__ V,
    const unsigned short* __restrict__ biasB, const int* __restrict__ mask,
    bf16* __restrict__ AT) {
    __shared__ unsigned short Qs[304 * QSTR];
    __shared__ unsigned short Ks[304 * QSTR];
    __shared__ unsigned short Vt[32 * PSTR];
    __shared__ unsigned short Pl[8 * 16 * PSTR];
    __shared__ int ms[320];
    const int tid = threadIdx.x;
    const int bw = blockIdx.x >> 3, h = blockIdx.x & 7;
    const size_t base = ((size_t)bw * HEADS + h) * NTOK * DH;
    const unsigned int* Qg = (const unsigned int*)(Q + base);
    const unsigned int* Kg = (const unsigned int*)(K + base);
    const unsigned int* Vg = (const unsigned int*)(V + base);
    for (int gg = tid; gg < NTOK * DH / 2; gg += 512) {
        int r = gg >> 4, d2 = (gg & 15) * 2;
        *(unsigned int*)&Qs[r * QSTR + d2] = Qg[gg];
        *(unsigned int*)&Ks[r * QSTR + d2] = Kg[gg];
        unsigned int uv = Vg[gg];
        Vt[d2 * PSTR + r]       = (unsigned short)(uv & 0xffffu);
        Vt[(d2 + 1) * PSTR + r] = (unsigned short)(uv >> 16);
    }
    for (int e = NTOK * QSTR + tid; e < 304 * QSTR; e += 512) { Qs[e] = 0; Ks[e] = 0; }
    for (int idx = tid; idx < 32 * (PSTR - NTOK); idx += 512) {
        int d = idx / (PSTR - NTOK), c = NTOK + idx % (PSTR - NTOK);
        Vt[d * PSTR + c] = 0;
    }
    for (int idx = tid; idx < 128 * (PSTR - 304); idx += 512) {
        int rr = idx / (PSTR - 304), c = 304 + idx % (PSTR - 304);
        Pl[rr * PSTR + c] = 0;
    }
    for (int j = tid; j < 320; j += 512) {
        int mv = 0;
        if (j < NTOK) { int a = j / 49, jr = j - a * 49; mv = mask[((size_t)bw * 49 + jr) * AGENT + a]; }
        ms[j] = mv;
    }
    __syncthreads();
    const int wave = tid >> 6, lane = tid & 63;
    const int li = lane & 15, g = lane >> 4;
    unsigned short* Pw = &Pl[wave * 16 * PSTR];
    unsigned int mb0 = 0, mb1 = 0, mb2 = 0;
    for (int jt = 0; jt < TP; jt++)
        for (int r = 0; r < 4; r++) {
            int j = jt * 16 + g * 4 + r;
            if (j < NTOK && ms[j]) {
                int bit = jt * 4 + r;
                if (bit < 32) mb0 |= (1u << bit);
                else if (bit < 64) mb1 |= (1u << (bit - 32));
                else mb2 |= (1u << (bit - 64));
            }
        }
    const ushort4* bb = (const ushort4*)biasB + (size_t)h * TP * TP * 64;
    for (int it = wave; it < TP; it += 8) {
        const s16x8 bq = *(const s16x8*)&Qs[(it * 16 + li) * QSTR + g * 8];
        f32x4 s[TP];
        #pragma unroll
        for (int jt = 0; jt < TP; jt++) {
            ushort4 bv = bb[(it * TP + jt) * 64 + lane];
            f32x4 c = {bfv(bv.x), bfv(bv.y), bfv(bv.z), bfv(bv.w)};
            s16x8 ak = *(const s16x8*)&Ks[(jt * 16 + li) * QSTR + g * 8];
            s[jt] = __builtin_amdgcn_mfma_f32_16x16x32_bf16(ak, bq, c, 0, 0, 0);
        }
        float mx = -INFINITY;
        #pragma unroll
        for (int jt = 0; jt < TP; jt++)
            #pragma unroll
            for (int r = 0; r < 4; r++) {
                int bit = jt * 4 + r;
                unsigned int w = (bit < 32) ? mb0 : (bit < 64) ? mb1 : mb2;
                float sv = ((w >> (bit & 31)) & 1u) ? s[jt][r] : -1e9f;
                if (jt == TP - 1 && g * 4 + r >= 6) sv = -INFINITY;
                s[jt][r] = sv;
                mx = fmaxf(mx, sv);
            }
        mx = fmaxf(mx, __shfl_xor(mx, 16));
        mx = fmaxf(mx, __shfl_xor(mx, 32));
        float sum = 0.f;
        #pragma unroll
        for (int jt = 0; jt < TP; jt++)
            #pragma unroll
            for (int r = 0; r < 4; r++) {
                float e = __expf(s[jt][r] - mx);
                s[jt][r] = e;
                sum += e;
            }
        sum += __shfl_xor(sum, 16);
        sum += __shfl_xor(sum, 32);
        const float inv = 1.0f / sum;
        #pragma unroll
        for (int jt = 0; jt < TP; jt++) {
            ushort4 pv;
            pv.x = f2bu(s[jt][0] * inv); pv.y = f2bu(s[jt][1] * inv);
            pv.z = f2bu(s[jt][2] * inv); pv.w = f2bu(s[jt][3] * inv);
            *(ushort4*)&Pw[li * PSTR + jt * 16 + g * 4] = pv;
        }
        f32x4 o0 = {0.f, 0.f, 0.f, 0.f}, o1 = {0.f, 0.f, 0.f, 0.f};
        #pragma unroll
        for (int kc = 0; kc < 10; kc++) {
            s16x8 ap = *(const s16x8*)&Pw[li * PSTR + kc * 32 + g * 8];
            s16x8 b0 = *(const s16x8*)&Vt[li * PSTR + kc * 32 + g * 8];
            s16x8 b1 = *(const s16x8*)&Vt[(li + 16) * PSTR + kc * 32 + g * 8];
            o0 = __builtin_amdgcn_mfma_f32_16x16x32_bf16(ap, b0, o0, 0, 0, 0);
            o1 = __builtin_amdgcn_mfma_f32_16x16x32_bf16(ap, b1, o1, 0, 0, 0);
        }
        #pragma unroll
        for (int r = 0; r < 4; r++) {
            int i = it * 16 + g * 4 + r;
            if (i < NTOK) {
                size_t ob = ((size_t)bw * NTOK + i) * DIM + h * DH;
                AT[ob + li]      = __float2bfloat16(o0[r]);
                AT[ob + 16 + li] = __float2bfloat16(o1[r]);
            }
        }
    }
}

// ---------- proj MFMA GEMM: stage AT-tile once, loop 4 e-chunks; f32 scatter out ----------
__global__ __launch_bounds__(256) void proj_mfma(
    const bf16* __restrict__ AT, const void* __restrict__ wout,
    float* __restrict__ out, const int* __restrict__ flag) {
    __shared__ unsigned short As[64 * GST];
    __shared__ unsigned short Bs[64 * GST];
    __shared__ int offA[64];
    const int tid = threadIdx.x;
    const int isf32 = *flag;
    const int mBase = blockIdx.x * 64;
    if (tid < 64) {
        int row = mBase + tid;                  // (bw, n) order
        int bw = row / NTOK, n = row - bw * NTOK;
        int b = bw >> 6, xx = (bw >> 3) & 7, yy = bw & 7;
        int l = n / 49, rr = n - l * 49, w1 = rr / 7, w2 = rr - w1 * 7;
        offA[tid] = ((((b * AGENT + l) * 8 + xx) * 8 + yy) * 7 + w1) * 7 + w2;
    }
    stage_tile(As, AT, (size_t)mBase, 0);       // AT is always bf16
    const int wave = tid >> 6, lane = tid & 63;
    const int li = lane & 15, g = lane >> 4;
    const int wm = wave & 1, wn = wave >> 1;
    for (int ec = 0; ec < 4; ec++) {
        __syncthreads();
        stage_tile(Bs, wout, (size_t)ec * 64, isf32);
        __syncthreads();
        f32x4 acc[2][2];
        #pragma unroll
        for (int mi = 0; mi < 2; mi++)
            #pragma unroll
            for (int ni = 0; ni < 2; ni++) acc[mi][ni] = (f32x4){0.f, 0.f, 0.f, 0.f};
        #pragma unroll
        for (int kc = 0; kc < 8; kc++) {
            const int ko = kc * 32 + g * 8;
            s16x8 a0 = *(const s16x8*)&As[(wm * 32 + li) * GST + ko];
            s16x8 a1 = *(const s16x8*)&As[(wm * 32 + 16 + li) * GST + ko];
            s16x8 b0 = *(const s16x8*)&Bs[(wn * 32 + li) * GST + ko];
            s16x8 b1 = *(const s16x8*)&Bs[(wn * 32 + 16 + li) * GST + ko];
            acc[0][0] = __builtin_amdgcn_mfma_f32_16x16x32_bf16(a0, b0, acc[0][0], 0, 0, 0);
            acc[0][1] = __builtin_amdgcn_mfma_f32_16x16x32_bf16(a0, b1, acc[0][1], 0, 0, 0);
            acc[1][0] = __builtin_amdgcn_mfma_f32_16x16x32_bf16(a1, b0, acc[1][0], 0, 0, 0);
            acc[1][1] = __builtin_amdgcn_mfma_f32_16x16x32_bf16(a1, b1, acc[1][1], 0, 0, 0);
        }
        #pragma unroll
        for (int ni = 0; ni < 2; ni++) {
            const int e = ec * 64 + wn * 32 + ni * 16 + li;
            #pragma unroll
            for (int mi = 0; mi < 2; mi++)
                #pragma unroll
                for (int r = 0; r < 4; r++) {
                    int ml = wm * 32 + mi * 16 + g * 4 + r;
                    out[(size_t)offA[ml] * DIM + e] = acc[mi][ni][r];
                }
        }
    }
}

extern "C" void kernel_launch(void* const* d_in, const int* in_sizes, int n_in,
                              void* d_out, int out_size, void* d_ws, size_t ws_size,
                              hipStream_t stream) {
    const long long SZ_X = 9633792, SZ_M = 37632, SZ_WQ = 196608, SZ_WO = 65536, SZ_BT = 14872;
    const void* x = d_in[0]; const void* maskp = d_in[1]; const void* wqkv = d_in[2];
    const void* wout = d_in[3]; const void* btab = d_in[4];
    for (int i = 0; i < n_in; i++) {
        long long s = in_sizes[i];
        if (s == SZ_X) x = d_in[i];
        else if (s == SZ_M) maskp = d_in[i];
        else if (s == SZ_WQ) wqkv = d_in[i];
        else if (s == SZ_WO) wout = d_in[i];
        else if (s == SZ_BT) btab = d_in[i];
    }
    const int* mask = (const int*)maskp;
    float* out = (float*)d_out;
    const size_t SZ = (size_t)BWIN * NTOK * DIM;
    bf16* Q  = (bf16*)d_ws;
    bf16* K  = Q + SZ;
    bf16* V  = K + SZ;
    bf16* AT = V + SZ;
    unsigned short* biasB = (unsigned short*)(AT + SZ);
    const size_t NBB = (size_t)HEADS * TP * TP * 64 * 4;
    int* flag = (int*)(biasB + NBB);
    detect_kernel<<<dim3(1), dim3(256), 0, stream>>>((const unsigned short*)x, flag);
    biasb_kernel<<<dim3((HEADS * TP * TP * 64 + 255) / 256), dim3(256), 0, stream>>>(btab, biasB, flag);
    qkv_mfma<<<dim3(588), dim3(256), 0, stream>>>(x, wqkv, Q, K, V, flag);
    attn_mfma<<<dim3(BWIN * HEADS), dim3(512), 0, stream>>>(Q, K, V, biasB, mask, AT);
    proj_mfma<<<dim3(588), dim3(256), 0, stream>>>(AT, wout, out, flag);
}